// Round 18
// baseline (4596.242 us; speedup 1.0000x reference)
//
#include <hip/hip_runtime.h>

typedef _Float16 half8 __attribute__((ext_vector_type(8)));
typedef _Float16 half4 __attribute__((ext_vector_type(4)));
typedef __fp16 fp16x2 __attribute__((ext_vector_type(2)));
typedef float floatx4 __attribute__((ext_vector_type(4)));
typedef unsigned int uintx4 __attribute__((ext_vector_type(4)));

#define CCH 256
#define LSEQ 8192
#define LTILE 128                 // output rows per block
#define HALO 4                    // 2 resblocks fused -> halo 4/side
#define AROWS 136                 // rows: l0-4 .. l0+131
#define NT 64                     // tiles per batch
#define ROWB 512
#define LDSB (AROWS * ROWB)       // 69632 -> 2 blocks/CU

__device__ __forceinline__ int swz(int row, int byte) {
  return row * ROWB + (byte ^ ((row & 7) << 4));
}
__device__ __forceinline__ floatx4 zero4() {
  floatx4 v; v[0] = 0.f; v[1] = 0.f; v[2] = 0.f; v[3] = 0.f; return v;
}
__device__ __forceinline__ unsigned long long pack4(float y0, float y1, float y2, float y3) {
  fp16x2 lo = __builtin_amdgcn_cvt_pkrtz(y0, y1);
  fp16x2 hi = __builtin_amdgcn_cvt_pkrtz(y2, y3);
  unsigned ulo = __builtin_bit_cast(unsigned, lo);
  unsigned uhi = __builtin_bit_cast(unsigned, hi);
  return (unsigned long long)ulo | ((unsigned long long)uhi << 32);
}

// shared conv MFMA loop (conv1 and conv2 have identical row mapping:
// out row w reads rows w-1..w+1). CLO clamps row<0 on first tile (only
// jtb==0,tap==0 can hit); CHI clamps row>AROWS-1 on last tile.
template <int NJT, bool CLO, bool CHI>
__device__ __forceinline__ void conv_mfma2(
    const _Float16* __restrict__ wsrc, size_t wbase, const char* smem,
    int jtb, int lrow, int kgrp, floatx4 (&acc)[5]) {
  const _Float16* wp = wsrc + wbase;
  half8 a0 = *(const half8*)(wp);
  half8 a1 = *(const half8*)(wp + 16 * 32);
  half8 a2 = *(const half8*)(wp + 32 * 32);
  half8 a3 = *(const half8*)(wp + 48 * 32);
  (void)a0;
  // acc layout note: caller passes per-i slices; we do full 4x here instead.
  (void)acc;
}

// Full conv: acc[4][5] (co-subtile i x j-tile). Kept as one function so the
// compiler schedules prefetch across the whole tile set.
template <int NJT, bool CLO, bool CHI>
__device__ __forceinline__ void conv_full(
    const _Float16* __restrict__ wsrc, size_t wbase, const char* smem,
    int jtb, int lrow, int kgrp, floatx4 (&acc)[4][5]) {
  const _Float16* wp = wsrc + wbase;
  half8 a0 = *(const half8*)(wp);
  half8 a1 = *(const half8*)(wp + 16 * 32);
  half8 a2 = *(const half8*)(wp + 32 * 32);
  half8 a3 = *(const half8*)(wp + 48 * 32);
  for (int it = 0; it < 24; ++it) {
    const int nit = (it < 23) ? it + 1 : it;
    const _Float16* np = wsrc + (size_t)nit * (CCH * 32) + wbase;
    half8 n0 = *(const half8*)(np);
    half8 n1 = *(const half8*)(np + 16 * 32);
    half8 n2 = *(const half8*)(np + 32 * 32);
    half8 n3 = *(const half8*)(np + 48 * 32);
    const int tap = it >> 3, kc = it & 7;
    const int byt = kc * 64 + kgrp * 16;
    __builtin_amdgcn_s_setprio(1);
#pragma unroll
    for (int jj = 0; jj < NJT; ++jj) {
      int row = (jtb + jj) * 16 + lrow + tap - 1;
      if (CLO && jj == 0) row = row < 0 ? 0 : row;
      if (CHI && jj == NJT - 1) row = row > AROWS - 1 ? AROWS - 1 : row;
      half8 bf = *(const half8*)(smem + swz(row, byt));
      acc[0][jj] = __builtin_amdgcn_mfma_f32_16x16x32_f16(a0, bf, acc[0][jj], 0, 0, 0);
      acc[1][jj] = __builtin_amdgcn_mfma_f32_16x16x32_f16(a1, bf, acc[1][jj], 0, 0, 0);
      acc[2][jj] = __builtin_amdgcn_mfma_f32_16x16x32_f16(a2, bf, acc[2][jj], 0, 0, 0);
      acc[3][jj] = __builtin_amdgcn_mfma_f32_16x16x32_f16(a3, bf, acc[3][jj], 0, 0, 0);
    }
    __builtin_amdgcn_s_setprio(0);
    a0 = n0; a1 = n1; a2 = n2; a3 = n3;
  }
}

// R18: fused2 — 2 resblocks per launch. Row w <-> l = l0-4+w. Per rb:
//   conv1(A-h) -> pk1(mask w in [1+2rb,135-2rb) & l-valid) ;
//   c2 = h*rs2+tsh (A-h) ; barrier ; pk1 -> A (w<136) ; barrier ;
//   conv2(A-r1) into c2 ; h' = c2*sc2p (mask w in [2+2rb,134-2rb) & l-valid)
//   rb0: h' -> A (w<136), barrier ; rb1: final -> dst for w in [4,132).
// MODE 1: up_block1 conv, clean 8 tiles (out w = otile*16+lrow+4).
template <int MODE>
__global__ __launch_bounds__(512, 1) void res9(
    const _Float16* __restrict__ src, _Float16* __restrict__ dst,
    const _Float16* __restrict__ wA, const _Float16* __restrict__ wB,
    const float* __restrict__ sc1v, const float* __restrict__ sh1v,
    const float* __restrict__ sc2pv, const float* __restrict__ rs2v,
    const float* __restrict__ tshv) {
  __shared__ __align__(16) char smem[LDSB];
  const int t = threadIdx.x;
  const int bx = blockIdx.x;
  const int b = bx >> 6;
  const int tile = bx & (NT - 1);
  const int l0 = tile * LTILE;

  // ---- stage A: 136 rows (row w <-> l = l0-4+w), f16, swizzled, zero-padded
  for (int c = t; c < AROWS * 32; c += 512) {
    const int row = c >> 5, col = c & 31;
    const int l = l0 + row - HALO;
    uintx4 v = {0u, 0u, 0u, 0u};
    if (l >= 0 && l < LSEQ)
      v = *(const uintx4*)(src + (((size_t)b * LSEQ + l) << 8) + col * 8);
    *(uintx4*)(smem + swz(row, col * 16)) = v;
  }
  __syncthreads();

  const int w = t >> 6, ln = t & 63;
  const int cg = w >> 1, lgrp = w & 1;  // co-group 0..3, l-half 0..1
  const int lrow = ln & 15, kgrp = ln >> 4;
  const size_t wbase = (size_t)(cg * 64 + lrow) * 32 + kgrp * 8;

  if constexpr (MODE == 0) {
    // j-tiles: lgrp0 -> 5 tiles (w 0..79), lgrp1 -> 4 tiles (w 80..143, clamped)
    const int jtb = lgrp ? 5 : 0;
    const int njt = lgrp ? 4 : 5;
    for (int rb = 0; rb < 2; ++rb) {
      const int wlo1 = 1 + 2 * rb, whi1 = 135 - 2 * rb;   // r1 validity
      const int wlo2 = 2 + 2 * rb, whi2 = 134 - 2 * rb;   // h' validity
      // ---- conv1
      floatx4 acc[4][5];
#pragma unroll
      for (int i = 0; i < 4; ++i)
#pragma unroll
        for (int j = 0; j < 5; ++j) acc[i][j] = zero4();
      if (lgrp == 0) conv_full<5, true, false>(wA, wbase, smem, 0, lrow, kgrp, acc);
      else           conv_full<4, false, true>(wA, wbase, smem, 5, lrow, kgrp, acc);
      // ---- pack r1 (masked)
      unsigned long long pk1[4][5];
#pragma unroll
      for (int i = 0; i < 4; ++i) {
        const int co = cg * 64 + i * 16 + kgrp * 4;
        floatx4 s = *(const floatx4*)(sc1v + co);
        floatx4 sh = *(const floatx4*)(sh1v + co);
#pragma unroll
        for (int jj = 0; jj < 5; ++jj) {
          if (jj < njt) {
            const int wr = (jtb + jj) * 16 + lrow;
            const int l = l0 - HALO + wr;
            const float m = (wr >= wlo1 && wr < whi1 && l >= 0 && l < LSEQ) ? 1.f : 0.f;
            pk1[i][jj] = pack4(
                fmaxf(acc[i][jj][0] * s[0] + sh[0], 0.f) * m,
                fmaxf(acc[i][jj][1] * s[1] + sh[1], 0.f) * m,
                fmaxf(acc[i][jj][2] * s[2] + sh[2], 0.f) * m,
                fmaxf(acc[i][jj][3] * s[3] + sh[3], 0.f) * m);
          }
        }
      }
      // ---- c2 C-init from h (A): c2 = h*rs2 + tsh
      floatx4 c2[4][5];
#pragma unroll
      for (int i = 0; i < 4; ++i) {
        const int co = cg * 64 + i * 16 + kgrp * 4;
        floatx4 rs = *(const floatx4*)(rs2v + co);
        floatx4 ts = *(const floatx4*)(tshv + co);
#pragma unroll
        for (int jj = 0; jj < 5; ++jj) {
          if (jj < njt) {
            int wr = (jtb + jj) * 16 + lrow;
            if (wr > AROWS - 1) wr = AROWS - 1;
            half4 h = *(const half4*)(smem + swz(wr, co * 2));
#pragma unroll
            for (int q = 0; q < 4; ++q)
              c2[i][jj][q] = (float)h[q] * rs[q] + ts[q];
          }
        }
      }
      __syncthreads();  // all A reads done before r1 overwrites
      // ---- store r1 -> A (rows < AROWS only)
#pragma unroll
      for (int i = 0; i < 4; ++i) {
        const int co = cg * 64 + i * 16 + kgrp * 4;
#pragma unroll
        for (int jj = 0; jj < 5; ++jj) {
          if (jj < njt) {
            const int wr = (jtb + jj) * 16 + lrow;
            if (wr < AROWS)
              *(unsigned long long*)(smem + swz(wr, co * 2)) = pk1[i][jj];
          }
        }
      }
      __syncthreads();
      // ---- conv2 into c2
      if (lgrp == 0) conv_full<5, true, false>(wB, wbase, smem, 0, lrow, kgrp, c2);
      else           conv_full<4, false, true>(wB, wbase, smem, 5, lrow, kgrp, c2);
      // ---- epi: h' = c2 * sc2p
      if (rb == 0) {
#pragma unroll
        for (int i = 0; i < 4; ++i) {
          const int co = cg * 64 + i * 16 + kgrp * 4;
          floatx4 sp = *(const floatx4*)(sc2pv + co);
#pragma unroll
          for (int jj = 0; jj < 5; ++jj) {
            if (jj < njt) {
              const int wr = (jtb + jj) * 16 + lrow;
              const int l = l0 - HALO + wr;
              const float m = (wr >= wlo2 && wr < whi2 && l >= 0 && l < LSEQ) ? 1.f : 0.f;
              unsigned long long pk = pack4(
                  c2[i][jj][0] * sp[0] * m, c2[i][jj][1] * sp[1] * m,
                  c2[i][jj][2] * sp[2] * m, c2[i][jj][3] * sp[3] * m);
              if (wr < AROWS)
                *(unsigned long long*)(smem + swz(wr, co * 2)) = pk;
            }
          }
        }
        __syncthreads();
      } else {
        // final: write rows w in [4,132) -> l = l0-4+w in [l0, l0+128)
#pragma unroll
        for (int i = 0; i < 4; ++i) {
          const int co = cg * 64 + i * 16 + kgrp * 4;
          floatx4 sp = *(const floatx4*)(sc2pv + co);
#pragma unroll
          for (int jj = 0; jj < 5; ++jj) {
            if (jj < njt) {
              const int wr = (jtb + jj) * 16 + lrow;
              if (wr >= 4 && wr < 132) {
                const int l = l0 - HALO + wr;
                const size_t off = (((size_t)b * LSEQ + l) << 8) + co;
                unsigned long long pk = pack4(
                    c2[i][jj][0] * sp[0], c2[i][jj][1] * sp[1],
                    c2[i][jj][2] * sp[2], c2[i][jj][3] * sp[3]);
                *(unsigned long long*)(dst + off) = pk;
              }
            }
          }
        }
      }
    }
  } else {
    // MODE 1: out row w = otile*16 + lrow + 4, 8 clean tiles (4 per lgrp)
    floatx4 acc[4][4];
#pragma unroll
    for (int i = 0; i < 4; ++i)
#pragma unroll
      for (int j = 0; j < 4; ++j) acc[i][j] = zero4();
    {
      const _Float16* wp = wA + wbase;
      half8 a0 = *(const half8*)(wp);
      half8 a1 = *(const half8*)(wp + 16 * 32);
      half8 a2 = *(const half8*)(wp + 32 * 32);
      half8 a3 = *(const half8*)(wp + 48 * 32);
      for (int it = 0; it < 24; ++it) {
        const int nit = (it < 23) ? it + 1 : it;
        const _Float16* np = wA + (size_t)nit * (CCH * 32) + wbase;
        half8 n0 = *(const half8*)(np);
        half8 n1 = *(const half8*)(np + 16 * 32);
        half8 n2 = *(const half8*)(np + 32 * 32);
        half8 n3 = *(const half8*)(np + 48 * 32);
        const int tap = it >> 3, kc = it & 7;
        const int byt = kc * 64 + kgrp * 16;
        __builtin_amdgcn_s_setprio(1);
#pragma unroll
        for (int j = 0; j < 4; ++j) {
          const int row = (lgrp * 4 + j) * 16 + lrow + 3 + tap;  // 3..133
          half8 bf = *(const half8*)(smem + swz(row, byt));
          acc[0][j] = __builtin_amdgcn_mfma_f32_16x16x32_f16(a0, bf, acc[0][j], 0, 0, 0);
          acc[1][j] = __builtin_amdgcn_mfma_f32_16x16x32_f16(a1, bf, acc[1][j], 0, 0, 0);
          acc[2][j] = __builtin_amdgcn_mfma_f32_16x16x32_f16(a2, bf, acc[2][j], 0, 0, 0);
          acc[3][j] = __builtin_amdgcn_mfma_f32_16x16x32_f16(a3, bf, acc[3][j], 0, 0, 0);
        }
        __builtin_amdgcn_s_setprio(0);
        a0 = n0; a1 = n1; a2 = n2; a3 = n3;
      }
    }
#pragma unroll
    for (int i = 0; i < 4; ++i) {
      const int co = cg * 64 + i * 16 + kgrp * 4;
      floatx4 s = *(const floatx4*)(sc1v + co);
      floatx4 sh = *(const floatx4*)(sh1v + co);
#pragma unroll
      for (int j = 0; j < 4; ++j) {
        const int l = l0 + (lgrp * 4 + j) * 16 + lrow;
        unsigned long long pk = pack4(
            fmaxf(acc[i][j][0] * s[0] + sh[0], 0.f),
            fmaxf(acc[i][j][1] * s[1] + sh[1], 0.f),
            fmaxf(acc[i][j][2] * s[2] + sh[2], 0.f),
            fmaxf(acc[i][j][3] * s[3] + sh[3], 0.f));
        *(unsigned long long*)(dst + (((size_t)b * LSEQ + l) << 8) + co) = pk;
      }
    }
  }
}

// x[16][1][8192] -> h0[b][l][co] (f16) = relu(conv1d_{1->256}(x) + b_in)
__global__ void conv_in_kernel(const float* __restrict__ x, const float* __restrict__ w_in,
                               const float* __restrict__ b_in, _Float16* __restrict__ hout) {
  size_t idx = (size_t)blockIdx.x * blockDim.x + threadIdx.x;
  int co = (int)(idx & 255);
  size_t pos = idx >> 8;
  int l = (int)(pos & (LSEQ - 1));
  int b = (int)(pos >> 13);
  float acc = b_in[co];
#pragma unroll
  for (int k = 0; k < 3; ++k) {
    int lg = l + k - 1;
    if (lg >= 0 && lg < LSEQ) acc += w_in[co * 3 + k] * x[(size_t)b * LSEQ + lg];
  }
  hout[idx] = (_Float16)fmaxf(acc, 0.f);
}

// final conv 256->4 + bias + relu + pixel-shuffle: out[b][l*4+co]
__global__ __launch_bounds__(256) void conv_u2_kernel(
    const _Float16* __restrict__ hin, const float* __restrict__ w2T4 /*[tap][ci][4]*/,
    const float* __restrict__ b_u2, float* __restrict__ out) {
  const size_t idx = (size_t)blockIdx.x * 256 + threadIdx.x;  // = b*8192 + l
  const int l = (int)(idx & (LSEQ - 1));
  const int b = (int)(idx >> 13);
  floatx4 acc = *(const floatx4*)b_u2;
  for (int tap = 0; tap < 3; ++tap) {
    const int lg = l + tap - 1;
    if (lg < 0 || lg >= LSEQ) continue;
    const half8* hp = (const half8*)(hin + (((size_t)b * LSEQ + lg) << 8));
    const floatx4* wp = (const floatx4*)(w2T4 + tap * 1024);
    for (int q = 0; q < 32; ++q) {
      half8 hv = hp[q];
#pragma unroll
      for (int r = 0; r < 8; ++r) {
        floatx4 wv = wp[q * 8 + r];
        float h = (float)hv[r];
        acc[0] += h * wv[0]; acc[1] += h * wv[1]; acc[2] += h * wv[2]; acc[3] += h * wv[3];
      }
    }
  }
  floatx4 y;
#pragma unroll
  for (int r = 0; r < 4; ++r) y[r] = fmaxf(acc[r], 0.f);
  *(floatx4*)(out + ((size_t)b << 15) + (size_t)l * 4) = y;
}

// weight transforms (DENSE layout) + BN folding (+ conv2 fold constants)
__global__ void prep_kernel(
    const float* __restrict__ w_r1, const float* __restrict__ w_r2,
    const float* __restrict__ w_u1, const float* __restrict__ w_u2,
    const float* __restrict__ b_r1, const float* __restrict__ g1,
    const float* __restrict__ be1, const float* __restrict__ m1, const float* __restrict__ v1,
    const float* __restrict__ b_r2, const float* __restrict__ g2,
    const float* __restrict__ be2, const float* __restrict__ m2, const float* __restrict__ v2,
    const float* __restrict__ b_u1,
    _Float16* __restrict__ wT1, _Float16* __restrict__ wT2, _Float16* __restrict__ wTu1,
    float* __restrict__ wu2T4,
    float* __restrict__ sc1, float* __restrict__ sh1,
    float* __restrict__ sc2p, float* __restrict__ rs2, float* __restrict__ tsh,
    float* __restrict__ scu1, float* __restrict__ shu1) {
  int idx = blockIdx.x * blockDim.x + threadIdx.x;
  if (idx < 3 * CCH * CCH) {
    int tap = idx >> 16;
    int rem = idx & 65535;
    int kc = rem >> 13;
    int rem2 = rem & 8191;
    int co = rem2 >> 5, c = rem2 & 31;
    int ci = kc * 32 + c;
    size_t s = ((size_t)co * CCH + ci) * 3 + tap;
    wT1[idx] = (_Float16)w_r1[s];
    wT2[idx] = (_Float16)w_r2[s];
    wTu1[idx] = (_Float16)w_u1[s];
  }
  if (idx < 3 * CCH * 4) {
    int co = idx & 3;
    int ci = (idx >> 2) & 255;
    int tap = idx >> 10;
    wu2T4[idx] = w_u2[((size_t)co * CCH + ci) * 3 + tap];
  }
  if (idx < CCH) {
    float s1 = g1[idx] * rsqrtf(v1[idx] + 1e-5f);
    sc1[idx] = s1;
    sh1[idx] = (b_r1[idx] - m1[idx]) * s1 + be1[idx];
    float s2 = g2[idx] * rsqrtf(v2[idx] + 1e-5f);
    float sh2 = (b_r2[idx] - m2[idx]) * s2 + be2[idx];
    float sp = 0.15f * s2;
    sc2p[idx] = sp;
    rs2[idx] = 1.0f / sp;
    tsh[idx] = sh2 / s2;
    scu1[idx] = 1.f;
    shu1[idx] = b_u1[idx];
  }
}

__global__ void diag_kernel(float* out, float v) { out[0] = v; }

extern "C" void kernel_launch(void* const* d_in, const int* in_sizes, int n_in,
                              void* d_out, int out_size, void* d_ws, size_t ws_size,
                              hipStream_t stream) {
  (void)in_sizes; (void)n_in; (void)out_size;
  const size_t HELEMS = (size_t)16 * LSEQ * CCH;      // 33,554,432
  const size_t HB = HELEMS * sizeof(_Float16);        // 67,108,864
  const size_t NEED = 2 * HB + 2u * 1024 * 1024;      // ~136 MiB
  if (ws_size < NEED) {
    diag_kernel<<<1, 1, 0, stream>>>((float*)d_out, 1000.0f + (float)(ws_size >> 20));
    return;
  }
  const float* x    = (const float*)d_in[0];
  const float* w_in = (const float*)d_in[3];
  const float* b_in = (const float*)d_in[4];
  const float* w_r1 = (const float*)d_in[5];
  const float* b_r1 = (const float*)d_in[6];
  const float* g1   = (const float*)d_in[7];
  const float* be1  = (const float*)d_in[8];
  const float* m1   = (const float*)d_in[9];
  const float* v1   = (const float*)d_in[10];
  const float* w_r2 = (const float*)d_in[11];
  const float* b_r2 = (const float*)d_in[12];
  const float* g2   = (const float*)d_in[13];
  const float* be2  = (const float*)d_in[14];
  const float* m2   = (const float*)d_in[15];
  const float* v2   = (const float*)d_in[16];
  const float* w_u1 = (const float*)d_in[17];
  const float* b_u1 = (const float*)d_in[18];
  const float* w_u2 = (const float*)d_in[19];
  const float* b_u2 = (const float*)d_in[20];

  char* ws = (char*)d_ws;
  _Float16* buf0 = (_Float16*)ws;
  _Float16* buf1 = (_Float16*)(ws + HB);
  _Float16* wT1  = (_Float16*)(ws + 2 * HB);
  _Float16* wT2  = wT1 + 3 * CCH * CCH;
  _Float16* wTu1 = wT2 + 3 * CCH * CCH;
  float* sc1  = (float*)(wTu1 + 3 * CCH * CCH);
  float* sh1  = sc1 + CCH;
  float* sc2p = sh1 + CCH;
  float* rs2  = sc2p + CCH;
  float* tsh  = rs2 + CCH;
  float* scu1 = tsh + CCH;
  float* shu1 = scu1 + CCH;
  float* wu2T4 = shu1 + CCH;

  prep_kernel<<<768, 256, 0, stream>>>(w_r1, w_r2, w_u1, w_u2, b_r1, g1, be1, m1, v1,
                                       b_r2, g2, be2, m2, v2, b_u1,
                                       wT1, wT2, wTu1, wu2T4, sc1, sh1, sc2p, rs2, tsh,
                                       scu1, shu1);
  conv_in_kernel<<<131072, 256, 0, stream>>>(x, w_in, b_in, buf0);
  const int grid = 16 * NT;  // 1024
  for (int k = 0; k < 16; ++k) {  // 16 launches x 2 fused resblocks = 32
    const _Float16* s = (k & 1) ? buf1 : buf0;
    _Float16* d = (k & 1) ? buf0 : buf1;
    res9<0><<<grid, 512, 0, stream>>>(s, d, wT1, wT2, sc1, sh1, sc2p, rs2, tsh);
  }
  // state in buf0 after 16 launches
  res9<1><<<grid, 512, 0, stream>>>(buf0, buf1, wTu1, (const _Float16*)nullptr,
                                    scu1, shu1, (const float*)nullptr,
                                    (const float*)nullptr, (const float*)nullptr);
  conv_u2_kernel<<<512, 256, 0, stream>>>(buf1, wu2T4, b_u2, (float*)d_out);
}

// Round 20
// 4437.805 us; speedup vs baseline: 1.0357x; 1.0357x over previous
//
#include <hip/hip_runtime.h>

typedef _Float16 half8 __attribute__((ext_vector_type(8)));
typedef _Float16 half4 __attribute__((ext_vector_type(4)));
typedef __fp16 fp16x2 __attribute__((ext_vector_type(2)));
typedef float floatx4 __attribute__((ext_vector_type(4)));
typedef unsigned int uintx4 __attribute__((ext_vector_type(4)));

#define CCH 256
#define LSEQ 8192
#define LTILE 128                 // output rows per block
#define HALO 4                    // 2 resblocks fused -> halo 4/side
#define AROWS 136                 // rows: l0-4 .. l0+131
#define NT 64                     // tiles per batch
#define ROWB 512
#define LDSB (AROWS * ROWB)       // 69632 -> 2 blocks/CU

__device__ __forceinline__ int swz(int row, int byte) {
  return row * ROWB + (byte ^ ((row & 7) << 4));
}
__device__ __forceinline__ floatx4 zero4() {
  floatx4 v; v[0] = 0.f; v[1] = 0.f; v[2] = 0.f; v[3] = 0.f; return v;
}
__device__ __forceinline__ unsigned long long pack4(float y0, float y1, float y2, float y3) {
  fp16x2 lo = __builtin_amdgcn_cvt_pkrtz(y0, y1);
  fp16x2 hi = __builtin_amdgcn_cvt_pkrtz(y2, y3);
  unsigned ulo = __builtin_bit_cast(unsigned, lo);
  unsigned uhi = __builtin_bit_cast(unsigned, hi);
  return (unsigned long long)ulo | ((unsigned long long)uhi << 32);
}

// Shared conv MFMA loop: out row w reads rows w-1..w+1. CLO clamps row<0 on
// first tile; CHI clamps row>AROWS-1 on last tile.
template <int NJT, bool CLO, bool CHI>
__device__ __forceinline__ void conv_full(
    const _Float16* __restrict__ wsrc, size_t wbase, const char* smem,
    int jtb, int lrow, int kgrp, floatx4 (&acc)[4][5]) {
  const _Float16* wp = wsrc + wbase;
  half8 a0 = *(const half8*)(wp);
  half8 a1 = *(const half8*)(wp + 16 * 32);
  half8 a2 = *(const half8*)(wp + 32 * 32);
  half8 a3 = *(const half8*)(wp + 48 * 32);
  for (int it = 0; it < 24; ++it) {
    const int nit = (it < 23) ? it + 1 : it;
    const _Float16* np = wsrc + (size_t)nit * (CCH * 32) + wbase;
    half8 n0 = *(const half8*)(np);
    half8 n1 = *(const half8*)(np + 16 * 32);
    half8 n2 = *(const half8*)(np + 32 * 32);
    half8 n3 = *(const half8*)(np + 48 * 32);
    const int tap = it >> 3, kc = it & 7;
    const int byt = kc * 64 + kgrp * 16;
    __builtin_amdgcn_s_setprio(1);
#pragma unroll
    for (int jj = 0; jj < NJT; ++jj) {
      int row = (jtb + jj) * 16 + lrow + tap - 1;
      if (CLO && jj == 0) row = row < 0 ? 0 : row;
      if (CHI && jj == NJT - 1) row = row > AROWS - 1 ? AROWS - 1 : row;
      half8 bf = *(const half8*)(smem + swz(row, byt));
      acc[0][jj] = __builtin_amdgcn_mfma_f32_16x16x32_f16(a0, bf, acc[0][jj], 0, 0, 0);
      acc[1][jj] = __builtin_amdgcn_mfma_f32_16x16x32_f16(a1, bf, acc[1][jj], 0, 0, 0);
      acc[2][jj] = __builtin_amdgcn_mfma_f32_16x16x32_f16(a2, bf, acc[2][jj], 0, 0, 0);
      acc[3][jj] = __builtin_amdgcn_mfma_f32_16x16x32_f16(a3, bf, acc[3][jj], 0, 0, 0);
    }
    __builtin_amdgcn_s_setprio(0);
    a0 = n0; a1 = n1; a2 = n2; a3 = n3;
  }
}

// R20 = R19 + RACE FIX: in rb0, a __syncthreads() between conv2 (which reads
// r1 from A) and the h' store into A. R18/R19 lacked it — fast waves
// overwrote r1 rows other waves were still reading (R18 masked by lucky
// scheduling; R19's hpk snapshot exposed it -> absmax 1.35e-2).
// MODE 0 per rb: conv1 -> pk1 ; hpk=h(LDS,u64) ; bar ; pk1->A ; bar ;
//   c2 = unpack(hpk)*rs2+tsh ; conv2 into c2 ; [rb0: bar ; h'->A ; bar]
//   [rb1: final -> dst].
// MODE 1: up_block1 conv.
template <int MODE>
__global__ __launch_bounds__(512, 1) void res11(
    const _Float16* __restrict__ src, _Float16* __restrict__ dst,
    const _Float16* __restrict__ wA, const _Float16* __restrict__ wB,
    const float* __restrict__ sc1v, const float* __restrict__ sh1v,
    const float* __restrict__ sc2pv, const float* __restrict__ rs2v,
    const float* __restrict__ tshv) {
  __shared__ __align__(16) char smem[LDSB];
  const int t = threadIdx.x;
  const int bx = blockIdx.x;
  const int b = bx >> 6;
  const int tile = bx & (NT - 1);
  const int l0 = tile * LTILE;

  // ---- stage A: 136 rows (row w <-> l = l0-4+w), f16, swizzled, zero-padded
  for (int c = t; c < AROWS * 32; c += 512) {
    const int row = c >> 5, col = c & 31;
    const int l = l0 + row - HALO;
    uintx4 v = {0u, 0u, 0u, 0u};
    if (l >= 0 && l < LSEQ)
      v = *(const uintx4*)(src + (((size_t)b * LSEQ + l) << 8) + col * 8);
    *(uintx4*)(smem + swz(row, col * 16)) = v;
  }
  __syncthreads();

  const int w = t >> 6, ln = t & 63;
  const int cg = w >> 1, lgrp = w & 1;  // co-group 0..3, l-half 0..1
  const int lrow = ln & 15, kgrp = ln >> 4;
  const size_t wbase = (size_t)(cg * 64 + lrow) * 32 + kgrp * 8;

  if constexpr (MODE == 0) {
    const int jtb = lgrp ? 5 : 0;
    const int njt = lgrp ? 4 : 5;
    for (int rb = 0; rb < 2; ++rb) {
      const int wlo1 = 1 + 2 * rb, whi1 = 135 - 2 * rb;   // r1 validity
      const int wlo2 = 2 + 2 * rb, whi2 = 134 - 2 * rb;   // h' validity
      // ---- conv1
      floatx4 acc[4][5];
#pragma unroll
      for (int i = 0; i < 4; ++i)
#pragma unroll
        for (int j = 0; j < 5; ++j) acc[i][j] = zero4();
      if (lgrp == 0) conv_full<5, true, false>(wA, wbase, smem, 0, lrow, kgrp, acc);
      else           conv_full<4, false, true>(wA, wbase, smem, 5, lrow, kgrp, acc);
      // ---- pack r1 (masked); acc dies tile-by-tile
      unsigned long long pk1[4][5];
#pragma unroll
      for (int i = 0; i < 4; ++i) {
        const int co = cg * 64 + i * 16 + kgrp * 4;
        floatx4 s = *(const floatx4*)(sc1v + co);
        floatx4 sh = *(const floatx4*)(sh1v + co);
#pragma unroll
        for (int jj = 0; jj < 5; ++jj) {
          if (jj < njt) {
            const int wr = (jtb + jj) * 16 + lrow;
            const int l = l0 - HALO + wr;
            const float m = (wr >= wlo1 && wr < whi1 && l >= 0 && l < LSEQ) ? 1.f : 0.f;
            pk1[i][jj] = pack4(
                fmaxf(acc[i][jj][0] * s[0] + sh[0], 0.f) * m,
                fmaxf(acc[i][jj][1] * s[1] + sh[1], 0.f) * m,
                fmaxf(acc[i][jj][2] * s[2] + sh[2], 0.f) * m,
                fmaxf(acc[i][jj][3] * s[3] + sh[3], 0.f) * m);
          }
        }
      }
      // ---- snapshot h (already packed f16 in LDS) as raw u64 — no expansion
      unsigned long long hpk[4][5];
#pragma unroll
      for (int i = 0; i < 4; ++i) {
        const int co = cg * 64 + i * 16 + kgrp * 4;
#pragma unroll
        for (int jj = 0; jj < 5; ++jj) {
          if (jj < njt) {
            int wr = (jtb + jj) * 16 + lrow;
            if (wr > AROWS - 1) wr = AROWS - 1;
            hpk[i][jj] = *(const unsigned long long*)(smem + swz(wr, co * 2));
          }
        }
      }
      __syncthreads();  // all A reads done before r1 overwrites
      // ---- store r1 -> A
#pragma unroll
      for (int i = 0; i < 4; ++i) {
        const int co = cg * 64 + i * 16 + kgrp * 4;
#pragma unroll
        for (int jj = 0; jj < 5; ++jj) {
          if (jj < njt) {
            const int wr = (jtb + jj) * 16 + lrow;
            if (wr < AROWS)
              *(unsigned long long*)(smem + swz(wr, co * 2)) = pk1[i][jj];
          }
        }
      }
      __syncthreads();
      // ---- expand hpk -> c2 (conv2 C-init); pk1/hpk die here
      floatx4 c2[4][5];
#pragma unroll
      for (int i = 0; i < 4; ++i) {
        const int co = cg * 64 + i * 16 + kgrp * 4;
        floatx4 rs = *(const floatx4*)(rs2v + co);
        floatx4 ts = *(const floatx4*)(tshv + co);
#pragma unroll
        for (int jj = 0; jj < 5; ++jj) {
          if (jj < njt) {
            half4 h = __builtin_bit_cast(half4, hpk[i][jj]);
#pragma unroll
            for (int q = 0; q < 4; ++q)
              c2[i][jj][q] = (float)h[q] * rs[q] + ts[q];
          }
        }
      }
      // ---- conv2 into c2
      if (lgrp == 0) conv_full<5, true, false>(wB, wbase, smem, 0, lrow, kgrp, c2);
      else           conv_full<4, false, true>(wB, wbase, smem, 5, lrow, kgrp, c2);
      // ---- epi: h' = c2 * sc2p
      if (rb == 0) {
        __syncthreads();  // RACE FIX: all conv2 r1-reads drained before h' overwrites A
#pragma unroll
        for (int i = 0; i < 4; ++i) {
          const int co = cg * 64 + i * 16 + kgrp * 4;
          floatx4 sp = *(const floatx4*)(sc2pv + co);
#pragma unroll
          for (int jj = 0; jj < 5; ++jj) {
            if (jj < njt) {
              const int wr = (jtb + jj) * 16 + lrow;
              const int l = l0 - HALO + wr;
              const float m = (wr >= wlo2 && wr < whi2 && l >= 0 && l < LSEQ) ? 1.f : 0.f;
              unsigned long long pk = pack4(
                  c2[i][jj][0] * sp[0] * m, c2[i][jj][1] * sp[1] * m,
                  c2[i][jj][2] * sp[2] * m, c2[i][jj][3] * sp[3] * m);
              if (wr < AROWS)
                *(unsigned long long*)(smem + swz(wr, co * 2)) = pk;
            }
          }
        }
        __syncthreads();
      } else {
        // final: rows w in [4,132) -> l in [l0, l0+128)
#pragma unroll
        for (int i = 0; i < 4; ++i) {
          const int co = cg * 64 + i * 16 + kgrp * 4;
          floatx4 sp = *(const floatx4*)(sc2pv + co);
#pragma unroll
          for (int jj = 0; jj < 5; ++jj) {
            if (jj < njt) {
              const int wr = (jtb + jj) * 16 + lrow;
              if (wr >= 4 && wr < 132) {
                const int l = l0 - HALO + wr;
                const size_t off = (((size_t)b * LSEQ + l) << 8) + co;
                unsigned long long pk = pack4(
                    c2[i][jj][0] * sp[0], c2[i][jj][1] * sp[1],
                    c2[i][jj][2] * sp[2], c2[i][jj][3] * sp[3]);
                *(unsigned long long*)(dst + off) = pk;
              }
            }
          }
        }
      }
    }
  } else {
    // MODE 1: out row w = otile*16 + lrow + 4, 8 clean tiles (4 per lgrp)
    floatx4 acc[4][4];
#pragma unroll
    for (int i = 0; i < 4; ++i)
#pragma unroll
      for (int j = 0; j < 4; ++j) acc[i][j] = zero4();
    {
      const _Float16* wp = wA + wbase;
      half8 a0 = *(const half8*)(wp);
      half8 a1 = *(const half8*)(wp + 16 * 32);
      half8 a2 = *(const half8*)(wp + 32 * 32);
      half8 a3 = *(const half8*)(wp + 48 * 32);
      for (int it = 0; it < 24; ++it) {
        const int nit = (it < 23) ? it + 1 : it;
        const _Float16* np = wA + (size_t)nit * (CCH * 32) + wbase;
        half8 n0 = *(const half8*)(np);
        half8 n1 = *(const half8*)(np + 16 * 32);
        half8 n2 = *(const half8*)(np + 32 * 32);
        half8 n3 = *(const half8*)(np + 48 * 32);
        const int tap = it >> 3, kc = it & 7;
        const int byt = kc * 64 + kgrp * 16;
        __builtin_amdgcn_s_setprio(1);
#pragma unroll
        for (int j = 0; j < 4; ++j) {
          const int row = (lgrp * 4 + j) * 16 + lrow + 3 + tap;  // 3..133
          half8 bf = *(const half8*)(smem + swz(row, byt));
          acc[0][j] = __builtin_amdgcn_mfma_f32_16x16x32_f16(a0, bf, acc[0][j], 0, 0, 0);
          acc[1][j] = __builtin_amdgcn_mfma_f32_16x16x32_f16(a1, bf, acc[1][j], 0, 0, 0);
          acc[2][j] = __builtin_amdgcn_mfma_f32_16x16x32_f16(a2, bf, acc[2][j], 0, 0, 0);
          acc[3][j] = __builtin_amdgcn_mfma_f32_16x16x32_f16(a3, bf, acc[3][j], 0, 0, 0);
        }
        __builtin_amdgcn_s_setprio(0);
        a0 = n0; a1 = n1; a2 = n2; a3 = n3;
      }
    }
#pragma unroll
    for (int i = 0; i < 4; ++i) {
      const int co = cg * 64 + i * 16 + kgrp * 4;
      floatx4 s = *(const floatx4*)(sc1v + co);
      floatx4 sh = *(const floatx4*)(sh1v + co);
#pragma unroll
      for (int j = 0; j < 4; ++j) {
        const int l = l0 + (lgrp * 4 + j) * 16 + lrow;
        unsigned long long pk = pack4(
            fmaxf(acc[i][j][0] * s[0] + sh[0], 0.f),
            fmaxf(acc[i][j][1] * s[1] + sh[1], 0.f),
            fmaxf(acc[i][j][2] * s[2] + sh[2], 0.f),
            fmaxf(acc[i][j][3] * s[3] + sh[3], 0.f));
        *(unsigned long long*)(dst + (((size_t)b * LSEQ + l) << 8) + co) = pk;
      }
    }
  }
}

// x[16][1][8192] -> h0[b][l][co] (f16) = relu(conv1d_{1->256}(x) + b_in)
__global__ void conv_in_kernel(const float* __restrict__ x, const float* __restrict__ w_in,
                               const float* __restrict__ b_in, _Float16* __restrict__ hout) {
  size_t idx = (size_t)blockIdx.x * blockDim.x + threadIdx.x;
  int co = (int)(idx & 255);
  size_t pos = idx >> 8;
  int l = (int)(pos & (LSEQ - 1));
  int b = (int)(pos >> 13);
  float acc = b_in[co];
#pragma unroll
  for (int k = 0; k < 3; ++k) {
    int lg = l + k - 1;
    if (lg >= 0 && lg < LSEQ) acc += w_in[co * 3 + k] * x[(size_t)b * LSEQ + lg];
  }
  hout[idx] = (_Float16)fmaxf(acc, 0.f);
}

// final conv 256->4 + bias + relu + pixel-shuffle: out[b][l*4+co]
__global__ __launch_bounds__(256) void conv_u2_kernel(
    const _Float16* __restrict__ hin, const float* __restrict__ w2T4 /*[tap][ci][4]*/,
    const float* __restrict__ b_u2, float* __restrict__ out) {
  const size_t idx = (size_t)blockIdx.x * 256 + threadIdx.x;  // = b*8192 + l
  const int l = (int)(idx & (LSEQ - 1));
  const int b = (int)(idx >> 13);
  floatx4 acc = *(const floatx4*)b_u2;
  for (int tap = 0; tap < 3; ++tap) {
    const int lg = l + tap - 1;
    if (lg < 0 || lg >= LSEQ) continue;
    const half8* hp = (const half8*)(hin + (((size_t)b * LSEQ + lg) << 8));
    const floatx4* wp = (const floatx4*)(w2T4 + tap * 1024);
    for (int q = 0; q < 32; ++q) {
      half8 hv = hp[q];
#pragma unroll
      for (int r = 0; r < 8; ++r) {
        floatx4 wv = wp[q * 8 + r];
        float h = (float)hv[r];
        acc[0] += h * wv[0]; acc[1] += h * wv[1]; acc[2] += h * wv[2]; acc[3] += h * wv[3];
      }
    }
  }
  floatx4 y;
#pragma unroll
  for (int r = 0; r < 4; ++r) y[r] = fmaxf(acc[r], 0.f);
  *(floatx4*)(out + ((size_t)b << 15) + (size_t)l * 4) = y;
}

// weight transforms (DENSE layout) + BN folding (+ conv2 fold constants)
__global__ void prep_kernel(
    const float* __restrict__ w_r1, const float* __restrict__ w_r2,
    const float* __restrict__ w_u1, const float* __restrict__ w_u2,
    const float* __restrict__ b_r1, const float* __restrict__ g1,
    const float* __restrict__ be1, const float* __restrict__ m1, const float* __restrict__ v1,
    const float* __restrict__ b_r2, const float* __restrict__ g2,
    const float* __restrict__ be2, const float* __restrict__ m2, const float* __restrict__ v2,
    const float* __restrict__ b_u1,
    _Float16* __restrict__ wT1, _Float16* __restrict__ wT2, _Float16* __restrict__ wTu1,
    float* __restrict__ wu2T4,
    float* __restrict__ sc1, float* __restrict__ sh1,
    float* __restrict__ sc2p, float* __restrict__ rs2, float* __restrict__ tsh,
    float* __restrict__ scu1, float* __restrict__ shu1) {
  int idx = blockIdx.x * blockDim.x + threadIdx.x;
  if (idx < 3 * CCH * CCH) {
    int tap = idx >> 16;
    int rem = idx & 65535;
    int kc = rem >> 13;
    int rem2 = rem & 8191;
    int co = rem2 >> 5, c = rem2 & 31;
    int ci = kc * 32 + c;
    size_t s = ((size_t)co * CCH + ci) * 3 + tap;
    wT1[idx] = (_Float16)w_r1[s];
    wT2[idx] = (_Float16)w_r2[s];
    wTu1[idx] = (_Float16)w_u1[s];
  }
  if (idx < 3 * CCH * 4) {
    int co = idx & 3;
    int ci = (idx >> 2) & 255;
    int tap = idx >> 10;
    wu2T4[idx] = w_u2[((size_t)co * CCH + ci) * 3 + tap];
  }
  if (idx < CCH) {
    float s1 = g1[idx] * rsqrtf(v1[idx] + 1e-5f);
    sc1[idx] = s1;
    sh1[idx] = (b_r1[idx] - m1[idx]) * s1 + be1[idx];
    float s2 = g2[idx] * rsqrtf(v2[idx] + 1e-5f);
    float sh2 = (b_r2[idx] - m2[idx]) * s2 + be2[idx];
    float sp = 0.15f * s2;
    sc2p[idx] = sp;
    rs2[idx] = 1.0f / sp;
    tsh[idx] = sh2 / s2;
    scu1[idx] = 1.f;
    shu1[idx] = b_u1[idx];
  }
}

__global__ void diag_kernel(float* out, float v) { out[0] = v; }

extern "C" void kernel_launch(void* const* d_in, const int* in_sizes, int n_in,
                              void* d_out, int out_size, void* d_ws, size_t ws_size,
                              hipStream_t stream) {
  (void)in_sizes; (void)n_in; (void)out_size;
  const size_t HELEMS = (size_t)16 * LSEQ * CCH;      // 33,554,432
  const size_t HB = HELEMS * sizeof(_Float16);        // 67,108,864
  const size_t NEED = 2 * HB + 2u * 1024 * 1024;      // ~136 MiB
  if (ws_size < NEED) {
    diag_kernel<<<1, 1, 0, stream>>>((float*)d_out, 1000.0f + (float)(ws_size >> 20));
    return;
  }
  const float* x    = (const float*)d_in[0];
  const float* w_in = (const float*)d_in[3];
  const float* b_in = (const float*)d_in[4];
  const float* w_r1 = (const float*)d_in[5];
  const float* b_r1 = (const float*)d_in[6];
  const float* g1   = (const float*)d_in[7];
  const float* be1  = (const float*)d_in[8];
  const float* m1   = (const float*)d_in[9];
  const float* v1   = (const float*)d_in[10];
  const float* w_r2 = (const float*)d_in[11];
  const float* b_r2 = (const float*)d_in[12];
  const float* g2   = (const float*)d_in[13];
  const float* be2  = (const float*)d_in[14];
  const float* m2   = (const float*)d_in[15];
  const float* v2   = (const float*)d_in[16];
  const float* w_u1 = (const float*)d_in[17];
  const float* b_u1 = (const float*)d_in[18];
  const float* w_u2 = (const float*)d_in[19];
  const float* b_u2 = (const float*)d_in[20];

  char* ws = (char*)d_ws;
  _Float16* buf0 = (_Float16*)ws;
  _Float16* buf1 = (_Float16*)(ws + HB);
  _Float16* wT1  = (_Float16*)(ws + 2 * HB);
  _Float16* wT2  = wT1 + 3 * CCH * CCH;
  _Float16* wTu1 = wT2 + 3 * CCH * CCH;
  float* sc1  = (float*)(wTu1 + 3 * CCH * CCH);
  float* sh1  = sc1 + CCH;
  float* sc2p = sh1 + CCH;
  float* rs2  = sc2p + CCH;
  float* tsh  = rs2 + CCH;
  float* scu1 = tsh + CCH;
  float* shu1 = scu1 + CCH;
  float* wu2T4 = shu1 + CCH;

  prep_kernel<<<768, 256, 0, stream>>>(w_r1, w_r2, w_u1, w_u2, b_r1, g1, be1, m1, v1,
                                       b_r2, g2, be2, m2, v2, b_u1,
                                       wT1, wT2, wTu1, wu2T4, sc1, sh1, sc2p, rs2, tsh,
                                       scu1, shu1);
  conv_in_kernel<<<131072, 256, 0, stream>>>(x, w_in, b_in, buf0);
  const int grid = 16 * NT;  // 1024
  for (int k = 0; k < 16; ++k) {  // 16 launches x 2 fused resblocks = 32
    const _Float16* s = (k & 1) ? buf1 : buf0;
    _Float16* d = (k & 1) ? buf0 : buf1;
    res11<0><<<grid, 512, 0, stream>>>(s, d, wT1, wT2, sc1, sh1, sc2p, rs2, tsh);
  }
  // state in buf0 after 16 launches
  res11<1><<<grid, 512, 0, stream>>>(buf0, buf1, wTu1, (const _Float16*)nullptr,
                                     scu1, shu1, (const float*)nullptr,
                                     (const float*)nullptr, (const float*)nullptr);
  conv_u2_kernel<<<512, 256, 0, stream>>>(buf1, wu2T4, b_u2, (float*)d_out);
}

// Round 21
// 4320.924 us; speedup vs baseline: 1.0637x; 1.0271x over previous
//
#include <hip/hip_runtime.h>

typedef _Float16 half8 __attribute__((ext_vector_type(8)));
typedef _Float16 half4 __attribute__((ext_vector_type(4)));
typedef __fp16 fp16x2 __attribute__((ext_vector_type(2)));
typedef float floatx4 __attribute__((ext_vector_type(4)));
typedef unsigned int uintx4 __attribute__((ext_vector_type(4)));

#define CCH 256
#define LSEQ 8192
#define LTILE 128                 // output rows per block
#define AROWS 132                 // staged h rows: l0-2 .. l0+129
#define NT 64                     // tiles per batch = 8192/128
#define ROWB 512
#define LDSB (AROWS * ROWB)       // 67584 -> 2 blocks/CU

__device__ __forceinline__ int swz(int row, int byte) {
  return row * ROWB + (byte ^ ((row & 7) << 4));
}
__device__ __forceinline__ floatx4 zero4() {
  floatx4 v; v[0] = 0.f; v[1] = 0.f; v[2] = 0.f; v[3] = 0.f; return v;
}
__device__ __forceinline__ unsigned long long pack4(float y0, float y1, float y2, float y3) {
  fp16x2 lo = __builtin_amdgcn_cvt_pkrtz(y0, y1);
  fp16x2 hi = __builtin_amdgcn_cvt_pkrtz(y2, y3);
  unsigned ulo = __builtin_bit_cast(unsigned, lo);
  unsigned uhi = __builtin_bit_cast(unsigned, hi);
  return (unsigned long long)ulo | ((unsigned long long)uhi << 32);
}

// conv1 MFMA loop, specialized per lgrp: NJT j-tiles from JTB; CLAMP_LAST
// applies the AROWS-1 clamp only to the final tile (only place it can trigger).
template <int NJT, bool CLAMP_LAST>
__device__ __forceinline__ void conv1_mfma(
    const _Float16* __restrict__ wA, size_t wbase, const char* smem,
    int jtb, int lrow, int kgrp, floatx4 (&acc)[4][5]) {
  const _Float16* wp = wA + wbase;
  half8 a0 = *(const half8*)(wp);
  half8 a1 = *(const half8*)(wp + 16 * 32);
  half8 a2 = *(const half8*)(wp + 32 * 32);
  half8 a3 = *(const half8*)(wp + 48 * 32);
  for (int it = 0; it < 24; ++it) {
    const int nit = (it < 23) ? it + 1 : it;
    const _Float16* np = wA + (size_t)nit * (CCH * 32) + wbase;
    half8 n0 = *(const half8*)(np);
    half8 n1 = *(const half8*)(np + 16 * 32);
    half8 n2 = *(const half8*)(np + 32 * 32);
    half8 n3 = *(const half8*)(np + 48 * 32);
    const int tap = it >> 3, kc = it & 7;
    const int byt = kc * 64 + kgrp * 16;
    __builtin_amdgcn_s_setprio(1);
#pragma unroll
    for (int jj = 0; jj < NJT; ++jj) {
      int arow = (jtb + jj) * 16 + lrow + tap;
      if (CLAMP_LAST && jj == NJT - 1) arow = arow > AROWS - 1 ? AROWS - 1 : arow;
      half8 bf = *(const half8*)(smem + swz(arow, byt));
      acc[0][jj] = __builtin_amdgcn_mfma_f32_16x16x32_f16(a0, bf, acc[0][jj], 0, 0, 0);
      acc[1][jj] = __builtin_amdgcn_mfma_f32_16x16x32_f16(a1, bf, acc[1][jj], 0, 0, 0);
      acc[2][jj] = __builtin_amdgcn_mfma_f32_16x16x32_f16(a2, bf, acc[2][jj], 0, 0, 0);
      acc[3][jj] = __builtin_amdgcn_mfma_f32_16x16x32_f16(a3, bf, acc[3][jj], 0, 0, 0);
    }
    __builtin_amdgcn_s_setprio(0);
    a0 = n0; a1 = n1; a2 = n2; a3 = n3;
  }
}

// pre-epi1 pack, specialized: TAIL_MASK applies r<130 predicate only on last tile.
template <int NJT, bool TAIL_MASK>
__device__ __forceinline__ void epi1_pack(
    const floatx4 (&acc)[4][5], const float* __restrict__ sc1v,
    const float* __restrict__ sh1v, int cg, int kgrp, int jtb, int lrow, int l0,
    unsigned long long (&pk1)[4][5]) {
#pragma unroll
  for (int i = 0; i < 4; ++i) {
    const int co = cg * 64 + i * 16 + kgrp * 4;
    floatx4 s = *(const floatx4*)(sc1v + co);
    floatx4 sh = *(const floatx4*)(sh1v + co);
#pragma unroll
    for (int jj = 0; jj < NJT; ++jj) {
      const int r = (jtb + jj) * 16 + lrow;
      const int l = l0 - 1 + r;
      const float m = ((l >= 0) && (l < LSEQ)) ? 1.f : 0.f;
      pk1[i][jj] = pack4(
          fmaxf(acc[i][jj][0] * s[0] + sh[0], 0.f) * m,
          fmaxf(acc[i][jj][1] * s[1] + sh[1], 0.f) * m,
          fmaxf(acc[i][jj][2] * s[2] + sh[2], 0.f) * m,
          fmaxf(acc[i][jj][3] * s[3] + sh[3], 0.f) * m);
    }
  }
}

template <int NJT, bool TAIL_MASK>
__device__ __forceinline__ void epi1_store(
    const unsigned long long (&pk1)[4][5], char* smem, int cg, int kgrp,
    int jtb, int lrow) {
#pragma unroll
  for (int i = 0; i < 4; ++i) {
    const int co = cg * 64 + i * 16 + kgrp * 4;
#pragma unroll
    for (int jj = 0; jj < NJT; ++jj) {
      const int r = (jtb + jj) * 16 + lrow;
      if (!TAIL_MASK || jj < NJT - 1 || r < 130)
        *(unsigned long long*)(smem + swz(r, co * 2)) = pk1[i][jj];
    }
  }
}

// R21 = R17 verbatim (best verified: 147us/dispatch, 4.33ms, absmax 9.77e-4).
// fused2 (R18-R20) abandoned: structurally register-starved at 512thr/1blk
// (VGPR demand ~160 > 128 cap -> 230MB/dispatch scratch spill, 326us).
// This structure: single-resblock, dense weights [tap][kc][co][32ci],
// register weight prefetch + setprio, residual C-init fold (no global h
// re-read), pkrtz packed epilogues, lgrp-specialized mask-free MFMA loops.
// MODE 0: dst = src + 0.15*bn2(conv2(relu(bn1(conv1(src)))))
// MODE 1: dst = relu(conv(src)*sc + sh)
template <int MODE>
__global__ __launch_bounds__(512, 1) void res8(
    const _Float16* __restrict__ src, _Float16* __restrict__ dst,
    const _Float16* __restrict__ wA, const _Float16* __restrict__ wB,
    const float* __restrict__ sc1v, const float* __restrict__ sh1v,
    const float* __restrict__ sc2pv, const float* __restrict__ rs2v,
    const float* __restrict__ tshv) {
  __shared__ __align__(16) char smem[LDSB];
  const int t = threadIdx.x;
  const int bx = blockIdx.x;
  const int b = bx >> 6;
  const int tile = bx & (NT - 1);
  const int l0 = tile * LTILE;

  // ---- stage A: 132 rows (row <-> l = l0-2+row), f16, swizzled, zero-padded
  for (int c = t; c < AROWS * 32; c += 512) {
    const int row = c >> 5, col = c & 31;
    const int l = l0 + row - 2;
    uintx4 v = {0u, 0u, 0u, 0u};
    if (l >= 0 && l < LSEQ)
      v = *(const uintx4*)(src + (((size_t)b * LSEQ + l) << 8) + col * 8);
    *(uintx4*)(smem + swz(row, col * 16)) = v;
  }
  __syncthreads();

  const int w = t >> 6, ln = t & 63;
  const int cg = w >> 1, lgrp = w & 1;  // co-group 0..3, l-half 0..1
  const int lrow = ln & 15, kgrp = ln >> 4;
  const size_t wbase = (size_t)(cg * 64 + lrow) * 32 + kgrp * 8;

  if constexpr (MODE == 0) {
    // ---- conv1 -> acc; r1 rows r (l = l0-1+r), r 0..129 used.
    floatx4 acc[4][5];
#pragma unroll
    for (int i = 0; i < 4; ++i)
#pragma unroll
      for (int j = 0; j < 5; ++j) acc[i][j] = zero4();
    unsigned long long pk1[4][5];
    if (lgrp == 0) {
      conv1_mfma<5, false>(wA, wbase, smem, 0, lrow, kgrp, acc);
      epi1_pack<5, false>(acc, sc1v, sh1v, cg, kgrp, 0, lrow, l0, pk1);
    } else {
      conv1_mfma<4, true>(wA, wbase, smem, 5, lrow, kgrp, acc);
      epi1_pack<4, true>(acc, sc1v, sh1v, cg, kgrp, 5, lrow, l0, pk1);
    }
    // ---- conv2 C-init from h still in LDS A: c2 = h*rs2 + tsh
    floatx4 c2[4][4];
#pragma unroll
    for (int i = 0; i < 4; ++i) {
      const int co = cg * 64 + i * 16 + kgrp * 4;
      floatx4 rs = *(const floatx4*)(rs2v + co);
      floatx4 ts = *(const floatx4*)(tshv + co);
#pragma unroll
      for (int j = 0; j < 4; ++j) {
        const int v = (lgrp * 4 + j) * 16 + lrow;
        half4 h = *(const half4*)(smem + swz(v + 2, co * 2));
#pragma unroll
        for (int q = 0; q < 4; ++q)
          c2[i][j][q] = (float)h[q] * rs[q] + ts[q];
      }
    }
    __syncthreads();  // ALL A reads (conv1 + h) done before r1 overwrites
    // ---- epi1: store packed r1 -> A
    if (lgrp == 0) {
      epi1_store<5, false>(pk1, smem, cg, kgrp, 0, lrow);
    } else {
      epi1_store<4, true>(pk1, smem, cg, kgrp, 5, lrow);
    }
    __syncthreads();
    // ---- conv2: accumulate into c2; out row v reads r1 rows v..v+2 (no masks)
    {
      const _Float16* wp = wB + wbase;
      half8 a0 = *(const half8*)(wp);
      half8 a1 = *(const half8*)(wp + 16 * 32);
      half8 a2 = *(const half8*)(wp + 32 * 32);
      half8 a3 = *(const half8*)(wp + 48 * 32);
      for (int it = 0; it < 24; ++it) {
        const int nit = (it < 23) ? it + 1 : it;
        const _Float16* np = wB + (size_t)nit * (CCH * 32) + wbase;
        half8 n0 = *(const half8*)(np);
        half8 n1 = *(const half8*)(np + 16 * 32);
        half8 n2 = *(const half8*)(np + 32 * 32);
        half8 n3 = *(const half8*)(np + 48 * 32);
        const int tap = it >> 3, kc = it & 7;
        const int byt = kc * 64 + kgrp * 16;
        __builtin_amdgcn_s_setprio(1);
#pragma unroll
        for (int j = 0; j < 4; ++j) {
          const int brow = (lgrp * 4 + j) * 16 + lrow + tap;  // 0..129
          half8 bf = *(const half8*)(smem + swz(brow, byt));
          c2[0][j] = __builtin_amdgcn_mfma_f32_16x16x32_f16(a0, bf, c2[0][j], 0, 0, 0);
          c2[1][j] = __builtin_amdgcn_mfma_f32_16x16x32_f16(a1, bf, c2[1][j], 0, 0, 0);
          c2[2][j] = __builtin_amdgcn_mfma_f32_16x16x32_f16(a2, bf, c2[2][j], 0, 0, 0);
          c2[3][j] = __builtin_amdgcn_mfma_f32_16x16x32_f16(a3, bf, c2[3][j], 0, 0, 0);
        }
        __builtin_amdgcn_s_setprio(0);
        a0 = n0; a1 = n1; a2 = n2; a3 = n3;
      }
    }
    // ---- epi2: y = c2 * sc2p (RTE casts on the carry path), no global read
#pragma unroll
    for (int i = 0; i < 4; ++i) {
      const int co = cg * 64 + i * 16 + kgrp * 4;
      floatx4 sp = *(const floatx4*)(sc2pv + co);
#pragma unroll
      for (int j = 0; j < 4; ++j) {
        const int v = (lgrp * 4 + j) * 16 + lrow;
        const int l = l0 + v;
        const size_t off = (((size_t)b * LSEQ + l) << 8) + co;
        half4 o;
#pragma unroll
        for (int q = 0; q < 4; ++q)
          o[q] = (_Float16)(c2[i][j][q] * sp[q]);
        *(half4*)(dst + off) = o;
      }
    }
  } else {
    // MODE 1: out = relu(conv(A)*sc + sh); out row v reads A rows v+1..v+3
    floatx4 acc[4][4];
#pragma unroll
    for (int i = 0; i < 4; ++i)
#pragma unroll
      for (int j = 0; j < 4; ++j) acc[i][j] = zero4();
    for (int it = 0; it < 24; ++it) {
      const int tap = it >> 3, kc = it & 7;
      const _Float16* wp = wA + (size_t)it * (CCH * 32) + wbase;
      half8 a0 = *(const half8*)(wp);
      half8 a1 = *(const half8*)(wp + 16 * 32);
      half8 a2 = *(const half8*)(wp + 32 * 32);
      half8 a3 = *(const half8*)(wp + 48 * 32);
      const int byt = kc * 64 + kgrp * 16;
#pragma unroll
      for (int j = 0; j < 4; ++j) {
        const int arow = (lgrp * 4 + j) * 16 + lrow + 1 + tap;  // 1..130
        half8 bf = *(const half8*)(smem + swz(arow, byt));
        acc[0][j] = __builtin_amdgcn_mfma_f32_16x16x32_f16(a0, bf, acc[0][j], 0, 0, 0);
        acc[1][j] = __builtin_amdgcn_mfma_f32_16x16x32_f16(a1, bf, acc[1][j], 0, 0, 0);
        acc[2][j] = __builtin_amdgcn_mfma_f32_16x16x32_f16(a2, bf, acc[2][j], 0, 0, 0);
        acc[3][j] = __builtin_amdgcn_mfma_f32_16x16x32_f16(a3, bf, acc[3][j], 0, 0, 0);
      }
    }
#pragma unroll
    for (int i = 0; i < 4; ++i) {
      const int co = cg * 64 + i * 16 + kgrp * 4;
      floatx4 s = *(const floatx4*)(sc1v + co);
      floatx4 sh = *(const floatx4*)(sh1v + co);
#pragma unroll
      for (int j = 0; j < 4; ++j) {
        const int v = (lgrp * 4 + j) * 16 + lrow;
        const int l = l0 + v;
        unsigned long long pk = pack4(
            fmaxf(acc[i][j][0] * s[0] + sh[0], 0.f),
            fmaxf(acc[i][j][1] * s[1] + sh[1], 0.f),
            fmaxf(acc[i][j][2] * s[2] + sh[2], 0.f),
            fmaxf(acc[i][j][3] * s[3] + sh[3], 0.f));
        *(unsigned long long*)(dst + (((size_t)b * LSEQ + l) << 8) + co) = pk;
      }
    }
  }
}

// x[16][1][8192] -> h0[b][l][co] (f16) = relu(conv1d_{1->256}(x) + b_in)
__global__ void conv_in_kernel(const float* __restrict__ x, const float* __restrict__ w_in,
                               const float* __restrict__ b_in, _Float16* __restrict__ hout) {
  size_t idx = (size_t)blockIdx.x * blockDim.x + threadIdx.x;
  int co = (int)(idx & 255);
  size_t pos = idx >> 8;
  int l = (int)(pos & (LSEQ - 1));
  int b = (int)(pos >> 13);
  float acc = b_in[co];
#pragma unroll
  for (int k = 0; k < 3; ++k) {
    int lg = l + k - 1;
    if (lg >= 0 && lg < LSEQ) acc += w_in[co * 3 + k] * x[(size_t)b * LSEQ + lg];
  }
  hout[idx] = (_Float16)fmaxf(acc, 0.f);
}

// final conv 256->4 + bias + relu + pixel-shuffle: out[b][l*4+co]
__global__ __launch_bounds__(256) void conv_u2_kernel(
    const _Float16* __restrict__ hin, const float* __restrict__ w2T4 /*[tap][ci][4]*/,
    const float* __restrict__ b_u2, float* __restrict__ out) {
  const size_t idx = (size_t)blockIdx.x * 256 + threadIdx.x;  // = b*8192 + l
  const int l = (int)(idx & (LSEQ - 1));
  const int b = (int)(idx >> 13);
  floatx4 acc = *(const floatx4*)b_u2;
  for (int tap = 0; tap < 3; ++tap) {
    const int lg = l + tap - 1;
    if (lg < 0 || lg >= LSEQ) continue;
    const half8* hp = (const half8*)(hin + (((size_t)b * LSEQ + lg) << 8));
    const floatx4* wp = (const floatx4*)(w2T4 + tap * 1024);
    for (int q = 0; q < 32; ++q) {
      half8 hv = hp[q];
#pragma unroll
      for (int r = 0; r < 8; ++r) {
        floatx4 wv = wp[q * 8 + r];
        float h = (float)hv[r];
        acc[0] += h * wv[0]; acc[1] += h * wv[1]; acc[2] += h * wv[2]; acc[3] += h * wv[3];
      }
    }
  }
  floatx4 y;
#pragma unroll
  for (int r = 0; r < 4; ++r) y[r] = fmaxf(acc[r], 0.f);
  *(floatx4*)(out + ((size_t)b << 15) + (size_t)l * 4) = y;
}

// weight transforms (DENSE layout) + BN folding (+ conv2 fold constants)
__global__ void prep_kernel(
    const float* __restrict__ w_r1, const float* __restrict__ w_r2,
    const float* __restrict__ w_u1, const float* __restrict__ w_u2,
    const float* __restrict__ b_r1, const float* __restrict__ g1,
    const float* __restrict__ be1, const float* __restrict__ m1, const float* __restrict__ v1,
    const float* __restrict__ b_r2, const float* __restrict__ g2,
    const float* __restrict__ be2, const float* __restrict__ m2, const float* __restrict__ v2,
    const float* __restrict__ b_u1,
    _Float16* __restrict__ wT1, _Float16* __restrict__ wT2, _Float16* __restrict__ wTu1,
    float* __restrict__ wu2T4,
    float* __restrict__ sc1, float* __restrict__ sh1,
    float* __restrict__ sc2p, float* __restrict__ rs2, float* __restrict__ tsh,
    float* __restrict__ scu1, float* __restrict__ shu1) {
  int idx = blockIdx.x * blockDim.x + threadIdx.x;
  if (idx < 3 * CCH * CCH) {
    // dense dst layout [tap][kc][co][32]: idx = ((tap*8+kc)*256+co)*32+c
    int tap = idx >> 16;
    int rem = idx & 65535;
    int kc = rem >> 13;
    int rem2 = rem & 8191;
    int co = rem2 >> 5, c = rem2 & 31;
    int ci = kc * 32 + c;
    size_t s = ((size_t)co * CCH + ci) * 3 + tap;
    wT1[idx] = (_Float16)w_r1[s];
    wT2[idx] = (_Float16)w_r2[s];
    wTu1[idx] = (_Float16)w_u1[s];
  }
  if (idx < 3 * CCH * 4) {  // wu2T4[tap][ci][co]
    int co = idx & 3;
    int ci = (idx >> 2) & 255;
    int tap = idx >> 10;
    wu2T4[idx] = w_u2[((size_t)co * CCH + ci) * 3 + tap];
  }
  if (idx < CCH) {
    float s1 = g1[idx] * rsqrtf(v1[idx] + 1e-5f);
    sc1[idx] = s1;
    sh1[idx] = (b_r1[idx] - m1[idx]) * s1 + be1[idx];
    float s2 = g2[idx] * rsqrtf(v2[idx] + 1e-5f);
    float sh2 = (b_r2[idx] - m2[idx]) * s2 + be2[idx];
    float sp = 0.15f * s2;
    sc2p[idx] = sp;
    rs2[idx] = 1.0f / sp;
    tsh[idx] = sh2 / s2;   // = 0.15*sh2/sp
    scu1[idx] = 1.f;
    shu1[idx] = b_u1[idx];
  }
}

__global__ void diag_kernel(float* out, float v) { out[0] = v; }

extern "C" void kernel_launch(void* const* d_in, const int* in_sizes, int n_in,
                              void* d_out, int out_size, void* d_ws, size_t ws_size,
                              hipStream_t stream) {
  (void)in_sizes; (void)n_in; (void)out_size;
  const size_t HELEMS = (size_t)16 * LSEQ * CCH;      // 33,554,432
  const size_t HB = HELEMS * sizeof(_Float16);        // 67,108,864
  const size_t NEED = 2 * HB + 2u * 1024 * 1024;      // ~136 MiB
  if (ws_size < NEED) {
    diag_kernel<<<1, 1, 0, stream>>>((float*)d_out, 1000.0f + (float)(ws_size >> 20));
    return;
  }
  const float* x    = (const float*)d_in[0];
  const float* w_in = (const float*)d_in[3];
  const float* b_in = (const float*)d_in[4];
  const float* w_r1 = (const float*)d_in[5];
  const float* b_r1 = (const float*)d_in[6];
  const float* g1   = (const float*)d_in[7];
  const float* be1  = (const float*)d_in[8];
  const float* m1   = (const float*)d_in[9];
  const float* v1   = (const float*)d_in[10];
  const float* w_r2 = (const float*)d_in[11];
  const float* b_r2 = (const float*)d_in[12];
  const float* g2   = (const float*)d_in[13];
  const float* be2  = (const float*)d_in[14];
  const float* m2   = (const float*)d_in[15];
  const float* v2   = (const float*)d_in[16];
  const float* w_u1 = (const float*)d_in[17];
  const float* b_u1 = (const float*)d_in[18];
  const float* w_u2 = (const float*)d_in[19];
  const float* b_u2 = (const float*)d_in[20];

  char* ws = (char*)d_ws;
  _Float16* buf0 = (_Float16*)ws;
  _Float16* buf1 = (_Float16*)(ws + HB);
  _Float16* wT1  = (_Float16*)(ws + 2 * HB);
  _Float16* wT2  = wT1 + 3 * CCH * CCH;
  _Float16* wTu1 = wT2 + 3 * CCH * CCH;
  float* sc1  = (float*)(wTu1 + 3 * CCH * CCH);
  float* sh1  = sc1 + CCH;
  float* sc2p = sh1 + CCH;
  float* rs2  = sc2p + CCH;
  float* tsh  = rs2 + CCH;
  float* scu1 = tsh + CCH;
  float* shu1 = scu1 + CCH;
  float* wu2T4 = shu1 + CCH;

  prep_kernel<<<768, 256, 0, stream>>>(w_r1, w_r2, w_u1, w_u2, b_r1, g1, be1, m1, v1,
                                       b_r2, g2, be2, m2, v2, b_u1,
                                       wT1, wT2, wTu1, wu2T4, sc1, sh1, sc2p, rs2, tsh,
                                       scu1, shu1);
  conv_in_kernel<<<131072, 256, 0, stream>>>(x, w_in, b_in, buf0);
  const int grid = 16 * NT;  // 1024
  for (int k = 0; k < 32; ++k) {
    const _Float16* s = (k & 1) ? buf1 : buf0;
    _Float16* d = (k & 1) ? buf0 : buf1;
    res8<0><<<grid, 512, 0, stream>>>(s, d, wT1, wT2, sc1, sh1, sc2p, rs2, tsh);
  }
  // state in buf0 after 32 resblocks
  res8<1><<<grid, 512, 0, stream>>>(buf0, buf1, wTu1, (const _Float16*)nullptr,
                                    scu1, shu1, (const float*)nullptr,
                                    (const float*)nullptr, (const float*)nullptr);
  conv_u2_kernel<<<512, 256, 0, stream>>>(buf1, wu2T4, b_u2, (float*)d_out);
}